// Round 8
// baseline (450.401 us; speedup 1.0000x reference)
//
#include <hip/hip_runtime.h>
#include <math.h>

// Problem constants
#define NA    50
#define NT    50
#define HIDK  128
#define NH    32
#define NC    16
#define NB    32
#define SAT   2500    // NA*NT
#define NS    2450    // (NA-1)*NT
#define NOUT  512     // NH*NC

// ============ K0: PQ[j][k] = sum_c att[j][c] * W[(j%32)*16+c][k] ============
__global__ __launch_bounds__(256) void k0_pq(const float* __restrict__ W,
                                             const float* __restrict__ att_src,
                                             const float* __restrict__ att_dst,
                                             float* __restrict__ PQ) {
  int g = blockIdx.x * 256 + threadIdx.x;   // 8192 total
  int j = g >> 7, k = g & 127;
  int hh = j & 31;
  const float* att = (j < 32) ? att_src : att_dst;
  float acc = 0.f;
  #pragma unroll
  for (int c = 0; c < 16; ++c)
    acc = fmaf(att[hh * 16 + c], W[(size_t)(hh * 16 + c) * 128 + k], acc);
  PQ[g] = acc;
}

// ============ K2: bucket-decomposed attention, k1 fused ============
// R15: base = R12 (297.6us best; 512thr, 78.8KB, depth-2 F). Occupancy lever
// closed (R8/R9 LDS-shrink hurt traffic; R13/R14 1024-thr hurt barriers/
// balance, occ never materialized). New lever: fuse k1's GEMV into k2 --
// block (b,h) computes u=X_b.p_h (2500x128 dot) and dv=X_ego.q_h directly
// into sU/sD. Cost ~6-7us/CU (5000 wave-fma + 1250 loads + 1250 broadcast
// ds_reads per block); saves k1 kernel (~20us) + launch + 20MB u/dv traffic.
// Per-XCD co-resident set stays 2 slices = 2.5MB <= L2 -> FETCH ~30MB.
// Micro: wave-0 __shfl_up scan replaces tid0 51-iter serial scan (+offCur
// seed merged, one less barrier).
#define LOADG(B_, g_) do {                                                  \
    _Pragma("unroll")                                                       \
    for (int j = 0; j < 4; ++j) {                                           \
      int idx_ = base + 2 * ((g_) * 4 + j);                                 \
      e##B_[j] = sE[idx_]; s##B_[j] = sIdx[idx_];                           \
    }                                                                       \
    _Pragma("unroll")                                                       \
    for (int j = 0; j < 4; ++j)                                             \
      x##B_[j] = *(const float4*)(xb + (size_t)s##B_[j] * HIDK);            \
  } while (0)

#define COMPG(B_) do {                                                      \
    _Pragma("unroll")                                                       \
    for (int j = 0; j < 4; ++j) {                                           \
      float2 ee = e##B_[j]; float4 xx = x##B_[j];                           \
      a1[0]=fmaf(ee.x,xx.x,a1[0]); a1[1]=fmaf(ee.x,xx.y,a1[1]);             \
      a1[2]=fmaf(ee.x,xx.z,a1[2]); a1[3]=fmaf(ee.x,xx.w,a1[3]);             \
      a2[0]=fmaf(ee.y,xx.x,a2[0]); a2[1]=fmaf(ee.y,xx.y,a2[1]);             \
      a2[2]=fmaf(ee.y,xx.z,a2[2]); a2[3]=fmaf(ee.y,xx.w,a2[3]);             \
      z1 += ee.x; z2 += ee.y;                                               \
    }                                                                       \
  } while (0)

__global__ __launch_bounds__(512, 4) void k2_attn(
    const float* __restrict__ X,     // (32,2500,128)
    const float* __restrict__ PQ,    // (64,128)
    const float* __restrict__ W,     // (512,128)
    const float* __restrict__ bias,  // (512)
    float* __restrict__ out)
{
  const int id = blockIdx.x;
  const int b  = (id & 7) + 8 * (id >> 8);   // <=2 X-slices per XCD L2 window
  const int h  = (id >> 3) & 31;
  const int tid = threadIdx.x;

  __shared__ float Bb[2][51][129];   // [which][bucket][c]; c==128 = z   52.6 KB
  __shared__ float2 sE[NS];          // sorted (e1,e2)                   19.6 KB
  __shared__ unsigned short sIdx[NS];// sorted sat-index                  4.9 KB
  __shared__ float sPQv[256];        // p_h | q_h                         1.0 KB
  __shared__ float sTheta[50], sD[50], sF1[50], sF2[50];
  __shared__ int   sRank[50];
  __shared__ int   offs[52];
  __shared__ int   offCur[51];
  __shared__ float red[8];
  __shared__ float sMaxU;

  float* sU = &Bb[0][0][0];                       // alias (dead before F)
  unsigned short* sBeta = (unsigned short*)&Bb[1][0][0];  // alias (dead before F)

  const float* Xb = X + (size_t)b * SAT * HIDK;

  // ---- phase 1: stage p_h/q_h + zero counters ----
  if (tid < 128) {
    sPQv[tid]       = PQ[(size_t)h * 128 + tid];        // p_h
    sPQv[128 + tid] = PQ[(size_t)(32 + h) * 128 + tid]; // q_h
  }
  if (tid < 51) offCur[tid] = 0;
  __syncthreads();

  // ---- fused GEMV (was k1): u/dv computed in-block ----
  float mx = -1e30f;
  {
    const float4* p4 = (const float4*)sPQv;
    const float4* q4 = (const float4*)(sPQv + 128);
    #pragma unroll
    for (int k = 0; k < 5; ++k) {
      int row = tid + k * 512;
      if (row < SAT) {
        const float4* xr = (const float4*)(Xb + (size_t)row * HIDK);
        const float4* wp = (row < NT) ? q4 : p4;
        float4 acc4 = make_float4(0.f, 0.f, 0.f, 0.f);
        #pragma unroll
        for (int c4 = 0; c4 < 32; ++c4) {
          float4 x = xr[c4], w = wp[c4];
          acc4.x = fmaf(x.x, w.x, acc4.x);
          acc4.y = fmaf(x.y, w.y, acc4.y);
          acc4.z = fmaf(x.z, w.z, acc4.z);
          acc4.w = fmaf(x.w, w.w, acc4.w);
        }
        float acc = (acc4.x + acc4.y) + (acc4.z + acc4.w);
        if (row < NT) sD[row] = acc;
        else { sU[row - NT] = acc; mx = fmaxf(mx, acc); }
      }
    }
  }
  // ---- maxU reduce ----
  #pragma unroll
  for (int o = 32; o; o >>= 1) mx = fmaxf(mx, __shfl_xor(mx, o));
  if ((tid & 63) == 0) red[tid >> 6] = mx;
  __syncthreads();
  if (tid == 0) {
    float m2 = red[0];
    #pragma unroll
    for (int k = 1; k < 8; ++k) m2 = fmaxf(m2, red[k]);
    sMaxU = m2;
  }
  __syncthreads();
  const float maxU = sMaxU;

  // ---- theta rank-sort + per-query factors ----
  if (tid < 50) {
    float th = -sD[tid];
    int r = 0;
    for (int t2 = 0; t2 < 50; ++t2) {
      float th2 = -sD[t2];
      r += (th2 < th) || (th2 == th && t2 < tid);
    }
    sRank[tid] = r;
    sTheta[r] = th;
    float x = maxU + sD[tid];
    float L = (x >= 0.f) ? x : 0.2f * x;
    sF1[tid] = __expf(x - L);
    sF2[tid] = __expf(0.2f * x - L);
  }
  __syncthreads();

  // ---- histogram (store beta once; reuse in scatter) ----
  for (int i = tid; i < NS; i += 512) {
    float uu = sU[i];
    int lo = 0, hi = 50;
    while (lo < hi) { int mid = (lo + hi) >> 1; if (sTheta[mid] <= uu) lo = mid + 1; else hi = mid; }
    sBeta[i] = (unsigned short)lo;
    atomicAdd(&offCur[lo], 1);
  }
  __syncthreads();

  // ---- wave-0 parallel exclusive scan of 51 counts -> offs + offCur seed ----
  if (tid < 64) {
    int c = (tid < 51) ? offCur[tid] : 0;
    int inc = c;
    #pragma unroll
    for (int o = 1; o < 64; o <<= 1) {
      int n = __shfl_up(inc, o);
      if (tid >= o) inc += n;
    }
    if (tid < 51) { int ex = inc - c; offs[tid] = ex; offCur[tid] = ex; }
    if (tid == 50) offs[51] = inc;   // total = 2450
  }
  __syncthreads();

  // ---- scatter: sorted (e1,e2,satIdx) ----
  for (int i = tid; i < NS; i += 512) {
    float uu = sU[i];
    int beta = sBeta[i];
    int pos = atomicAdd(&offCur[beta], 1);
    sE[pos] = make_float2(__expf(uu - maxU), __expf(0.2f * (uu - maxU)));
    sIdx[pos] = (unsigned short)(i + NT);
  }
  __syncthreads();

  // ---- F: wave-owned segments, depth-2 software-pipelined gather ----
  {
    const int wave = tid >> 6;        // 0..7
    const int lane = tid & 63;
    const int slot = lane >> 5;       // which source of the pair
    const int cq   = lane & 31;       // channel quad cq*4..+3
    const float* xb = Xb + cq * 4;

    for (int seg = wave; seg < 51; seg += 8) {
      const int i0 = offs[seg], i1 = offs[seg + 1];
      const int base = i0 + slot;
      int np = i1 - base;                 // pairs this slot owns
      np = (np > 0) ? ((np + 1) >> 1) : 0;
      const int G = np >> 2;              // full groups of 4 pairs

      float a1[4] = {0.f, 0.f, 0.f, 0.f};
      float a2[4] = {0.f, 0.f, 0.f, 0.f};
      float z1 = 0.f, z2 = 0.f;

      float2 eA[4], eB[4]; int sA[4], sB[4]; float4 xA[4], xB[4];
      int g = 0;
      if (G) LOADG(A, 0);
      while (g + 2 <= G) {
        LOADG(B, g + 1);                  // prefetch next while computing cur
        COMPG(A);
        if (g + 2 < G) LOADG(A, g + 2);
        COMPG(B);
        g += 2;
      }
      if (g < G) COMPG(A);
      for (int k = G * 4; k < np; ++k) {  // remainder pairs
        int idx = base + 2 * k;
        float2 ee = sE[idx];
        int ss = sIdx[idx];
        float4 xx = *(const float4*)(xb + (size_t)ss * HIDK);
        a1[0]=fmaf(ee.x,xx.x,a1[0]); a1[1]=fmaf(ee.x,xx.y,a1[1]);
        a1[2]=fmaf(ee.x,xx.z,a1[2]); a1[3]=fmaf(ee.x,xx.w,a1[3]);
        a2[0]=fmaf(ee.y,xx.x,a2[0]); a2[1]=fmaf(ee.y,xx.y,a2[1]);
        a2[2]=fmaf(ee.y,xx.z,a2[2]); a2[3]=fmaf(ee.y,xx.w,a2[3]);
        z1 += ee.x; z2 += ee.y;
      }

      // combine the two slots; exclusive flush (no atomics, no zero-init)
      #pragma unroll
      for (int j = 0; j < 4; ++j) {
        a1[j] += __shfl_xor(a1[j], 32);
        a2[j] += __shfl_xor(a2[j], 32);
      }
      z1 += __shfl_xor(z1, 32);
      z2 += __shfl_xor(z2, 32);
      if (slot == 0) {
        #pragma unroll
        for (int j = 0; j < 4; ++j) {
          Bb[0][seg][cq * 4 + j] = a1[j];
          Bb[1][seg][cq * 4 + j] = a2[j];
        }
        if (cq == 0) { Bb[0][seg][128] = z1; Bb[1][seg][128] = z2; }
      }
    }
  }
  __syncthreads();

  // ---- stage W_h^T (aliases sE — dead after F) + scans ----
  float* WshT = (float*)sE;           // [128][16]
  const float* Wh = W + (size_t)h * 16 * 128;
  for (int v = tid; v < 2048; v += 512) {
    int k = v >> 4, cout = v & 15;
    WshT[k * 16 + cout] = Wh[(size_t)cout * 128 + k];
  }
  // scans over 51 buckets: which=0 -> exclusive suffix, which=1 -> inclusive prefix
  for (int task = tid; task < 258; task += 512) {
    int which = task >= 129;
    int c = task - which * 129;
    if (which == 0) {
      float run = 0.f;
      for (int k = 50; k >= 0; --k) { float tmp = Bb[0][k][c]; Bb[0][k][c] = run; run += tmp; }
    } else {
      float run = 0.f;
      for (int k = 0; k <= 50; ++k) { run += Bb[1][k][c]; Bb[1][k][c] = run; }
    }
  }
  __syncthreads();

  // ---- epilogue: project through W_h, divide, bias, store ego slice ----
  for (int task = tid; task < NT * NC; task += 512) {
    int t = task >> 4, cout = task & 15;
    int r = sRank[t];
    float F1 = sF1[t], F2 = sF2[t];
    float z = F1 * Bb[0][r][128] + F2 * Bb[1][r][128];
    const float* b1r = &Bb[0][r][0];
    const float* b2r = &Bb[1][r][0];
    float n1 = 0.f, n2 = 0.f;
    #pragma unroll 4
    for (int c = 0; c < 128; ++c) {
      float w = WshT[c * 16 + cout];
      n1 = fmaf(b1r[c], w, n1);
      n2 = fmaf(b2r[c], w, n2);
    }
    out[((size_t)b * SAT + t) * NOUT + h * 16 + cout] =
        (F1 * n1 + F2 * n2) / z + bias[h * 16 + cout];
  }

  // ---- fused bias fill of the non-ego region: fire-and-forget tail stores ----
  // 1024 blocks x 9800 float4 == 32 b x 313600 float4 (rows a>=1). Disjoint
  // from every block's ego-slice writes (a==0), so no barrier/race; stores
  // drain while other resident blocks compute. (proven R8/R9/R10/R12)
  {
    int g0 = id * 9800 + tid;
    const float4 b4 = ((const float4*)bias)[g0 & 127];  // constant per thread (stride 512 ≡ 0 mod 128)
    float4* o4 = (float4*)out;
    int gEnd = (id + 1) * 9800;
    for (int g = g0; g < gEnd; g += 512) {
      int bb2 = g / 313600;
      int o = g - bb2 * 313600;
      o4[(size_t)bb2 * 320000 + 6400 + o] = b4;
    }
  }
}

extern "C" void kernel_launch(void* const* d_in, const int* in_sizes, int n_in,
                              void* d_out, int out_size, void* d_ws, size_t ws_size,
                              hipStream_t stream) {
  const float* X       = (const float*)d_in[0];  // h (32,50,50,128)
  const float* Wm      = (const float*)d_in[1];  // W (512,128)
  const float* att_src = (const float*)d_in[2];  // (32,16)
  const float* att_dst = (const float*)d_in[3];  // (32,16)
  const float* bias    = (const float*)d_in[4];  // (512,)
  float* out = (float*)d_out;

  float* PQ = (float*)d_ws;

  hipLaunchKernelGGL(k0_pq, dim3(32), dim3(256), 0, stream, Wm, att_src, att_dst, PQ);
  hipLaunchKernelGGL(k2_attn, dim3(1024), dim3(512), 0, stream,
                     X, PQ, Wm, bias, out);
}

// Round 9
// 291.873 us; speedup vs baseline: 1.5431x; 1.5431x over previous
//
#include <hip/hip_runtime.h>
#include <math.h>

// Problem constants
#define NA    50
#define NT    50
#define HIDK  128
#define NH    32
#define NC    16
#define NB    32
#define SAT   2500    // NA*NT
#define NS    2450    // (NA-1)*NT
#define NOUT  512     // NH*NC

// ============ K0: PQ[j][k] = sum_c att[j][c] * W[(j%32)*16+c][k] ============
__global__ __launch_bounds__(256) void k0_pq(const float* __restrict__ W,
                                             const float* __restrict__ att_src,
                                             const float* __restrict__ att_dst,
                                             float* __restrict__ PQ) {
  int g = blockIdx.x * 256 + threadIdx.x;   // 8192 total
  int j = g >> 7, k = g & 127;
  int hh = j & 31;
  const float* att = (j < 32) ? att_src : att_dst;
  float acc = 0.f;
  #pragma unroll
  for (int c = 0; c < 16; ++c)
    acc = fmaf(att[hh * 16 + c], W[(size_t)(hh * 16 + c) * 128 + k], acc);
  PQ[g] = acc;
}

// ============ K1: u[b][h][s] = x_row . p_h ; d[b][h][t] = x_ego_row . q_h ============
// R16 note: k1 is permanent. Fusing its GEMV into k2 (R15) re-reads X 32x
// from L2 (1.28GB, ~37us floor) to save a ~26MB HBM round-trip (~8us) --
// structurally a bad trade regardless of coalescing.
__global__ __launch_bounds__(256) void k1_ud(
    const float* __restrict__ X,     // (80000,128)
    const float* __restrict__ PQ,    // (64,128)
    float* __restrict__ u,           // [b][h][2500]
    float* __restrict__ dv)          // [b][h][50]
{
  __shared__ float Ast[32][68];
  __shared__ float Bst[32][68];
  const int tid = threadIdx.x;
  const int m0 = blockIdx.x * 64;
  const int ty = tid >> 4, tx = tid & 15;
  float acc[4][4] = {};
  const int sr = tid >> 3, sc = tid & 7;

  for (int kc = 0; kc < 128; kc += 32) {
    #pragma unroll
    for (int L = 0; L < 2; ++L) {
      int row = sr + L * 32;
      float4 v = *(const float4*)&X[(size_t)(m0 + row) * 128 + kc + sc * 4];
      Ast[sc*4+0][row] = v.x; Ast[sc*4+1][row] = v.y;
      Ast[sc*4+2][row] = v.z; Ast[sc*4+3][row] = v.w;
      float4 w = *(const float4*)&PQ[(size_t)row * 128 + kc + sc * 4];
      Bst[sc*4+0][row] = w.x; Bst[sc*4+1][row] = w.y;
      Bst[sc*4+2][row] = w.z; Bst[sc*4+3][row] = w.w;
    }
    __syncthreads();
    #pragma unroll
    for (int k = 0; k < 32; ++k) {
      float4 a4 = *(const float4*)&Ast[k][ty * 4];
      float4 b4 = *(const float4*)&Bst[k][tx * 4];
      float a[4] = {a4.x, a4.y, a4.z, a4.w};
      float bb[4] = {b4.x, b4.y, b4.z, b4.w};
      #pragma unroll
      for (int i = 0; i < 4; ++i)
        #pragma unroll
        for (int j = 0; j < 4; ++j)
          acc[i][j] = fmaf(a[i], bb[j], acc[i][j]);
    }
    __syncthreads();
  }

  #pragma unroll
  for (int i = 0; i < 4; ++i) {
    int m = m0 + ty * 4 + i;
    int b = m / SAT, s = m - b * SAT;
    #pragma unroll
    for (int jj = 0; jj < 4; ++jj) {
      int col = tx * 4 + jj;
      if (col < 32)
        u[(size_t)(b * 32 + col) * SAT + s] = acc[i][jj];
      else if (s < NT)
        dv[(size_t)(b * 32 + col - 32) * NT + s] = acc[i][jj];
    }
  }
}

// ============ K2: bucket-decomposed attention in x-space ============
// R16: base = R12 (297.6us best). New: LPT work-stealing in F. Bucket sizes
// are spacing statistics (2450 u's between 50 order stats of a same-scale
// distribution) -> near-exponential, CV~1, max bucket ~190 vs mean 48. The
// static seg=wave+8k assignment makes F run at the slowest wave's speed
// (~1.3-1.5x mean). Fix: rank-sort segments by descending size (one wave,
// O(51^2), overlapped with scatter) + LDS atomic counter; waves grab
// segments largest-first. Exclusive flush preserved (one wave per segment).
// Also kept from R15 (correctness-proven): wave-0 shfl_up scan for offs
// (replaces tid0 serial scan, one less barrier).
#define LOADG(B_, g_) do {                                                  \
    _Pragma("unroll")                                                       \
    for (int j = 0; j < 4; ++j) {                                           \
      int idx_ = base + 2 * ((g_) * 4 + j);                                 \
      e##B_[j] = sE[idx_]; s##B_[j] = sIdx[idx_];                           \
    }                                                                       \
    _Pragma("unroll")                                                       \
    for (int j = 0; j < 4; ++j)                                             \
      x##B_[j] = *(const float4*)(xb + (size_t)s##B_[j] * HIDK);            \
  } while (0)

#define COMPG(B_) do {                                                      \
    _Pragma("unroll")                                                       \
    for (int j = 0; j < 4; ++j) {                                           \
      float2 ee = e##B_[j]; float4 xx = x##B_[j];                           \
      a1[0]=fmaf(ee.x,xx.x,a1[0]); a1[1]=fmaf(ee.x,xx.y,a1[1]);             \
      a1[2]=fmaf(ee.x,xx.z,a1[2]); a1[3]=fmaf(ee.x,xx.w,a1[3]);             \
      a2[0]=fmaf(ee.y,xx.x,a2[0]); a2[1]=fmaf(ee.y,xx.y,a2[1]);             \
      a2[2]=fmaf(ee.y,xx.z,a2[2]); a2[3]=fmaf(ee.y,xx.w,a2[3]);             \
      z1 += ee.x; z2 += ee.y;                                               \
    }                                                                       \
  } while (0)

__global__ __launch_bounds__(512, 4) void k2_attn(
    const float* __restrict__ X,     // (32,2500,128)
    const float* __restrict__ u,     // [b][h][2500]
    const float* __restrict__ dv,    // [b][h][50]
    const float* __restrict__ W,     // (512,128)
    const float* __restrict__ bias,  // (512)
    float* __restrict__ out)
{
  const int id = blockIdx.x;
  const int b  = (id & 7) + 8 * (id >> 8);   // <=2 X-slices per XCD L2 window
  const int h  = (id >> 3) & 31;
  const int tid = threadIdx.x;

  __shared__ float Bb[2][51][129];   // [which][bucket][c]; c==128 = z   52.6 KB
  __shared__ float2 sE[NS];          // sorted (e1,e2)                   19.6 KB
  __shared__ unsigned short sIdx[NS];// sorted sat-index                  4.9 KB
  __shared__ float sTheta[50], sD[50], sF1[50], sF2[50];
  __shared__ int   sRank[50];
  __shared__ int   offs[52];
  __shared__ int   offCur[51];
  __shared__ int   segOrder[51];
  __shared__ int   segCtr;
  __shared__ float red[8];
  __shared__ float sMaxU;

  float* sU = &Bb[0][0][0];                       // alias (dead before F)
  unsigned short* sBeta = (unsigned short*)&Bb[1][0][0];  // alias (dead before F)

  const size_t bh = (size_t)b * 32 + h;
  const float* uP = u + bh * SAT + NT;   // skip ego rows

  // ---- load u (+ fused running max), dv ----
  float mx = -1e30f;
  for (int i = tid; i < NS; i += 512) { float v = uP[i]; sU[i] = v; mx = fmaxf(mx, v); }
  if (tid < 50) sD[tid] = dv[bh * NT + tid];
  if (tid < 51) offCur[tid] = 0;
  #pragma unroll
  for (int o = 32; o; o >>= 1) mx = fmaxf(mx, __shfl_xor(mx, o));
  if ((tid & 63) == 0) red[tid >> 6] = mx;
  __syncthreads();
  if (tid == 0) {
    float m2 = red[0];
    #pragma unroll
    for (int k = 1; k < 8; ++k) m2 = fmaxf(m2, red[k]);
    sMaxU = m2;
  }
  __syncthreads();
  const float maxU = sMaxU;

  // ---- theta rank-sort + per-query factors ----
  if (tid < 50) {
    float th = -sD[tid];
    int r = 0;
    for (int t2 = 0; t2 < 50; ++t2) {
      float th2 = -sD[t2];
      r += (th2 < th) || (th2 == th && t2 < tid);
    }
    sRank[tid] = r;
    sTheta[r] = th;
    float x = maxU + sD[tid];
    float L = (x >= 0.f) ? x : 0.2f * x;
    sF1[tid] = __expf(x - L);
    sF2[tid] = __expf(0.2f * x - L);
  }
  __syncthreads();

  // ---- histogram (store beta once; reuse in scatter) ----
  for (int i = tid; i < NS; i += 512) {
    float uu = sU[i];
    int lo = 0, hi = 50;
    while (lo < hi) { int mid = (lo + hi) >> 1; if (sTheta[mid] <= uu) lo = mid + 1; else hi = mid; }
    sBeta[i] = (unsigned short)lo;
    atomicAdd(&offCur[lo], 1);
  }
  __syncthreads();

  // ---- wave-0 parallel exclusive scan of 51 counts -> offs + offCur seed ----
  if (tid < 64) {
    int c = (tid < 51) ? offCur[tid] : 0;
    int inc = c;
    #pragma unroll
    for (int o = 1; o < 64; o <<= 1) {
      int n = __shfl_up(inc, o);
      if (tid >= o) inc += n;
    }
    if (tid < 51) { int ex = inc - c; offs[tid] = ex; offCur[tid] = ex; }
    if (tid == 50) offs[51] = inc;   // total = 2450
  }
  __syncthreads();

  // ---- scatter (all threads) + LPT segment sort (tid<51, overlapped) ----
  if (tid < 51) {
    int sz = offs[tid + 1] - offs[tid];
    int r = 0;
    for (int t2 = 0; t2 < 51; ++t2) {
      int sz2 = offs[t2 + 1] - offs[t2];
      r += (sz2 > sz) || (sz2 == sz && t2 < tid);
    }
    segOrder[r] = tid;    // descending size
  }
  if (tid == 511) segCtr = 0;
  for (int i = tid; i < NS; i += 512) {
    float uu = sU[i];
    int beta = sBeta[i];
    int pos = atomicAdd(&offCur[beta], 1);
    sE[pos] = make_float2(__expf(uu - maxU), __expf(0.2f * (uu - maxU)));
    sIdx[pos] = (unsigned short)(i + NT);
  }
  __syncthreads();

  // ---- F: LPT work-stealing, depth-2 software-pipelined gather ----
  {
    const int lane = tid & 63;
    const int slot = lane >> 5;       // which source of the pair
    const int cq   = lane & 31;       // channel quad cq*4..+3
    const float* xb = X + (size_t)b * SAT * HIDK + cq * 4;

    for (;;) {
      int kidx = 0;
      if (lane == 0) kidx = atomicAdd(&segCtr, 1);
      kidx = __shfl(kidx, 0);
      if (kidx >= 51) break;
      const int seg = segOrder[kidx];

      const int i0 = offs[seg], i1 = offs[seg + 1];
      const int base = i0 + slot;
      int np = i1 - base;                 // pairs this slot owns
      np = (np > 0) ? ((np + 1) >> 1) : 0;
      const int G = np >> 2;              // full groups of 4 pairs

      float a1[4] = {0.f, 0.f, 0.f, 0.f};
      float a2[4] = {0.f, 0.f, 0.f, 0.f};
      float z1 = 0.f, z2 = 0.f;

      float2 eA[4], eB[4]; int sA[4], sB[4]; float4 xA[4], xB[4];
      int g = 0;
      if (G) LOADG(A, 0);
      while (g + 2 <= G) {
        LOADG(B, g + 1);                  // prefetch next while computing cur
        COMPG(A);
        if (g + 2 < G) LOADG(A, g + 2);
        COMPG(B);
        g += 2;
      }
      if (g < G) COMPG(A);
      for (int k = G * 4; k < np; ++k) {  // remainder pairs
        int idx = base + 2 * k;
        float2 ee = sE[idx];
        int ss = sIdx[idx];
        float4 xx = *(const float4*)(xb + (size_t)ss * HIDK);
        a1[0]=fmaf(ee.x,xx.x,a1[0]); a1[1]=fmaf(ee.x,xx.y,a1[1]);
        a1[2]=fmaf(ee.x,xx.z,a1[2]); a1[3]=fmaf(ee.x,xx.w,a1[3]);
        a2[0]=fmaf(ee.y,xx.x,a2[0]); a2[1]=fmaf(ee.y,xx.y,a2[1]);
        a2[2]=fmaf(ee.y,xx.z,a2[2]); a2[3]=fmaf(ee.y,xx.w,a2[3]);
        z1 += ee.x; z2 += ee.y;
      }

      // combine the two slots; exclusive flush (no atomics, no zero-init)
      #pragma unroll
      for (int j = 0; j < 4; ++j) {
        a1[j] += __shfl_xor(a1[j], 32);
        a2[j] += __shfl_xor(a2[j], 32);
      }
      z1 += __shfl_xor(z1, 32);
      z2 += __shfl_xor(z2, 32);
      if (slot == 0) {
        #pragma unroll
        for (int j = 0; j < 4; ++j) {
          Bb[0][seg][cq * 4 + j] = a1[j];
          Bb[1][seg][cq * 4 + j] = a2[j];
        }
        if (cq == 0) { Bb[0][seg][128] = z1; Bb[1][seg][128] = z2; }
      }
    }
  }
  __syncthreads();

  // ---- stage W_h^T (aliases sE — dead after F) + scans ----
  float* WshT = (float*)sE;           // [128][16]
  const float* Wh = W + (size_t)h * 16 * 128;
  for (int v = tid; v < 2048; v += 512) {
    int k = v >> 4, cout = v & 15;
    WshT[k * 16 + cout] = Wh[(size_t)cout * 128 + k];
  }
  // scans over 51 buckets: which=0 -> exclusive suffix, which=1 -> inclusive prefix
  for (int task = tid; task < 258; task += 512) {
    int which = task >= 129;
    int c = task - which * 129;
    if (which == 0) {
      float run = 0.f;
      for (int k = 50; k >= 0; --k) { float tmp = Bb[0][k][c]; Bb[0][k][c] = run; run += tmp; }
    } else {
      float run = 0.f;
      for (int k = 0; k <= 50; ++k) { run += Bb[1][k][c]; Bb[1][k][c] = run; }
    }
  }
  __syncthreads();

  // ---- epilogue: project through W_h, divide, bias, store ego slice ----
  for (int task = tid; task < NT * NC; task += 512) {
    int t = task >> 4, cout = task & 15;
    int r = sRank[t];
    float F1 = sF1[t], F2 = sF2[t];
    float z = F1 * Bb[0][r][128] + F2 * Bb[1][r][128];
    const float* b1r = &Bb[0][r][0];
    const float* b2r = &Bb[1][r][0];
    float n1 = 0.f, n2 = 0.f;
    #pragma unroll 4
    for (int c = 0; c < 128; ++c) {
      float w = WshT[c * 16 + cout];
      n1 = fmaf(b1r[c], w, n1);
      n2 = fmaf(b2r[c], w, n2);
    }
    out[((size_t)b * SAT + t) * NOUT + h * 16 + cout] =
        (F1 * n1 + F2 * n2) / z + bias[h * 16 + cout];
  }

  // ---- fused bias fill of the non-ego region: fire-and-forget tail stores ----
  // 1024 blocks x 9800 float4 == 32 b x 313600 float4 (rows a>=1). Disjoint
  // from every block's ego-slice writes (a==0), so no barrier/race; stores
  // drain while other resident blocks compute. (proven R8/R9/R10/R12)
  {
    int g0 = id * 9800 + tid;
    const float4 b4 = ((const float4*)bias)[g0 & 127];  // constant per thread (stride 512 ≡ 0 mod 128)
    float4* o4 = (float4*)out;
    int gEnd = (id + 1) * 9800;
    for (int g = g0; g < gEnd; g += 512) {
      int bb2 = g / 313600;
      int o = g - bb2 * 313600;
      o4[(size_t)bb2 * 320000 + 6400 + o] = b4;
    }
  }
}

extern "C" void kernel_launch(void* const* d_in, const int* in_sizes, int n_in,
                              void* d_out, int out_size, void* d_ws, size_t ws_size,
                              hipStream_t stream) {
  const float* X       = (const float*)d_in[0];  // h (32,50,50,128)
  const float* Wm      = (const float*)d_in[1];  // W (512,128)
  const float* att_src = (const float*)d_in[2];  // (32,16)
  const float* att_dst = (const float*)d_in[3];  // (32,16)
  const float* bias    = (const float*)d_in[4];  // (512,)
  float* out = (float*)d_out;

  float* PQ = (float*)d_ws;
  float* u  = PQ + 64 * 128;
  float* dv = u + (size_t)NB * NH * SAT;

  hipLaunchKernelGGL(k0_pq, dim3(32), dim3(256), 0, stream, Wm, att_src, att_dst, PQ);
  hipLaunchKernelGGL(k1_ud, dim3(1250), dim3(256), 0, stream, X, PQ, u, dv);
  hipLaunchKernelGGL(k2_attn, dim3(1024), dim3(512), 0, stream,
                     X, u, dv, Wm, bias, out);
}